// Round 4
// baseline (218.537 us; speedup 1.0000x reference)
//
#include <hip/hip_runtime.h>

#define WIRE_DIM  32
#define NUM_WIRES 64
#define BATCH     8192
#define HID       10
#define NB        2          // batches per wave; weight broadcasts amortized 2x

// broadcast-read a float from a wave-uniform lane index -> scalar
__device__ __forceinline__ float rl(float x, int slane) {
    return __uint_as_float(__builtin_amdgcn_readlane(__float_as_uint(x), slane));
}

__global__ __launch_bounds__(256) void isnet_kernel(
    const float* __restrict__ outputs,
    const int*   __restrict__ tests,
    const float* __restrict__ W1,
    const float* __restrict__ b1,
    const float* __restrict__ W2,
    const float* __restrict__ b2,
    float*       __restrict__ out)
{
    // W1 transposed: sW1t[h*64 + d] = W1[d*10 + h] -> per-h contiguous float4,
    // wave-uniform address => ds_read_b128 broadcast, zero bank conflicts
    __shared__ __align__(16) float sW1t[HID * 64];
    __shared__ float sB1[HID], sW2[HID], sB2;

    const int tid  = threadIdx.x;
    const int lane = tid & 63;
    const int wave = tid >> 6;

    for (int i = tid; i < 64 * HID; i += 256) {
        int d = i / HID, h = i - d * HID;
        sW1t[h * 64 + d] = W1[i];
    }
    if (tid < HID) { sB1[tid] = b1[tid]; sW2[tid] = W2[tid]; }
    if (tid == 0)  sB2 = b2[0];
    __syncthreads();

    // NB=2 batches per wave. Register budget by hand: w[2][8]=64 + acc 20 +
    // temps ~24 => ~110 live. NO waves-per-EU hint: round-2 showed the hint
    // forces a 64-VGPR budget and spills (WRITE_SIZE 646 MB); unhinted
    // allocator sizes to need (round 3: exactly 64 for NB=1).
    const int b0 = blockIdx.x * (4 * NB) + wave * NB;

    int sp[NB], sl[NB];
    #pragma unroll
    for (int nb = 0; nb < NB; ++nb) {
        sp[nb] = __builtin_amdgcn_readfirstlane(tests[2 * (b0 + nb)]);
        sl[nb] = __builtin_amdgcn_readfirstlane(tests[2 * (b0 + nb) + 1]);
    }

    // the ONLY HBM stream: each lane holds its own wire row (lane == wire)
    float4 w[NB][8];
    #pragma unroll
    for (int nb = 0; nb < NB; ++nb) {
        const float* row = outputs + (size_t)(b0 + nb) * (NUM_WIRES * WIRE_DIM)
                         + lane * WIRE_DIM;
        #pragma unroll
        for (int j = 0; j < 8; ++j) w[nb][j] = *(const float4*)(row + 4 * j);
    }

    float acc[NB][HID];
    #pragma unroll
    for (int nb = 0; nb < NB; ++nb)
        #pragma unroll
        for (int h = 0; h < HID; ++h) acc[nb][h] = sB1[h];

    #pragma unroll
    for (int j = 0; j < 8; ++j) {
        // person chunks: broadcast from the lane that owns them (no 2nd HBM stream)
        float px[NB], py[NB], pz[NB], pw[NB];
        #pragma unroll
        for (int nb = 0; nb < NB; ++nb) {
            px[nb] = rl(w[nb][j].x, sp[nb]);
            py[nb] = rl(w[nb][j].y, sp[nb]);
            pz[nb] = rl(w[nb][j].z, sp[nb]);
            pw[nb] = rl(w[nb][j].w, sp[nb]);
        }
        #pragma unroll
        for (int h = 0; h < HID; ++h) {
            // one pair of b128 broadcasts serves BOTH batches (the whole point)
            float4 wa = *(const float4*)&sW1t[h * 64 + 4 * j];        // person rows
            float4 wb = *(const float4*)&sW1t[h * 64 + 32 + 4 * j];   // wire rows
            #pragma unroll
            for (int nb = 0; nb < NB; ++nb)
                acc[nb][h] += px[nb] * wa.x + py[nb] * wa.y
                            + pz[nb] * wa.z + pw[nb] * wa.w
                            + w[nb][j].x * wb.x + w[nb][j].y * wb.y
                            + w[nb][j].z * wb.z + w[nb][j].w * wb.w;
        }
    }

    // relu -> W2 -> logit per lane(=wire) -> wave softmax -> loss
    #pragma unroll
    for (int nb = 0; nb < NB; ++nb) {
        float v = sB2;
        #pragma unroll
        for (int h = 0; h < HID; ++h) v += fmaxf(acc[nb][h], 0.f) * sW2[h];

        float m = v;
        #pragma unroll
        for (int off = 32; off > 0; off >>= 1) m = fmaxf(m, __shfl_xor(m, off));
        float e = __expf(v - m);
        float s = e;
        #pragma unroll
        for (int off = 32; off > 0; off >>= 1) s += __shfl_xor(s, off);
        float lv = rl(v, sl[nb]);                       // logit at `location`
        if (lane == 0) out[b0 + nb] = m + __logf(s) - lv;  // -log_softmax[loc]
    }
}

extern "C" void kernel_launch(void* const* d_in, const int* in_sizes, int n_in,
                              void* d_out, int out_size, void* d_ws, size_t ws_size,
                              hipStream_t stream) {
    const float* outputs = (const float*)d_in[0];
    const int*   tests   = (const int*)d_in[1];
    const float* W1      = (const float*)d_in[2];
    const float* b1      = (const float*)d_in[3];
    const float* W2      = (const float*)d_in[4];
    const float* b2      = (const float*)d_in[5];
    float* out = (float*)d_out;

    // 8 batches per block (4 waves x NB=2) -> 1024 blocks, all resident
    isnet_kernel<<<BATCH / (4 * NB), 256, 0, stream>>>(
        outputs, tests, W1, b1, W2, b2, out);
}

// Round 5
// 159.163 us; speedup vs baseline: 1.3730x; 1.3730x over previous
//
#include <hip/hip_runtime.h>

#define WIRE_DIM  32
#define NUM_WIRES 64
#define BATCH     8192
#define HID       10
#define NB        2          // batches per wave; weight broadcasts amortized 2x

// broadcast-read a float from a wave-uniform lane index -> scalar
__device__ __forceinline__ float rl(float x, int slane) {
    return __uint_as_float(__builtin_amdgcn_readlane(__float_as_uint(x), slane));
}

__global__ __launch_bounds__(256) void isnet_kernel(
    const float* __restrict__ outputs,
    const int*   __restrict__ tests,
    const float* __restrict__ W1,
    const float* __restrict__ b1,
    const float* __restrict__ W2,
    const float* __restrict__ b2,
    float*       __restrict__ out)
{
    // W1 transposed: sW1t[h*64 + d] = W1[d*10 + h] -> per-h contiguous float4,
    // wave-uniform address => ds_read_b128 broadcast, zero bank conflicts.
    __shared__ __align__(16) float sW1t[HID * 64];
    __shared__ float sB1[HID], sW2[HID], sB2;

    const int tid  = threadIdx.x;
    const int lane = tid & 63;
    const int wave = tid >> 6;

    for (int i = tid; i < 64 * HID; i += 256) {
        int d = i / HID, h = i - d * HID;
        sW1t[h * 64 + d] = W1[i];
    }
    if (tid < HID) { sB1[tid] = b1[tid]; sW2[tid] = W2[tid]; }
    if (tid == 0)  sB2 = b2[0];
    __syncthreads();

    // ROLLED j-loop (#pragma unroll 1): rounds 1/2/4 all spilled because the
    // fully-unrolled load-rich body let the scheduler hoist loads en masse
    // (R4: VGPR=256 + 219 MB spill WRITE with only ~110 hand-counted live).
    // Rolling the loop caps the hoisting scope to one iteration.
    const int b0 = blockIdx.x * (4 * NB) + wave * NB;

    const int sp0 = __builtin_amdgcn_readfirstlane(tests[2 * b0]);
    const int sl0 = __builtin_amdgcn_readfirstlane(tests[2 * b0 + 1]);
    const int sp1 = __builtin_amdgcn_readfirstlane(tests[2 * b0 + 2]);
    const int sl1 = __builtin_amdgcn_readfirstlane(tests[2 * b0 + 3]);

    // the ONLY HBM stream: each lane owns its wire row (lane == wire)
    const float* row0 = outputs + (size_t)(b0 + 0) * (NUM_WIRES * WIRE_DIM) + lane * WIRE_DIM;
    const float* row1 = outputs + (size_t)(b0 + 1) * (NUM_WIRES * WIRE_DIM) + lane * WIRE_DIM;

    float acc0[HID], acc1[HID];
    #pragma unroll
    for (int h = 0; h < HID; ++h) { acc0[h] = sB1[h]; acc1[h] = sB1[h]; }

    // one-stage software pipeline: prefetch j+1 while computing j
    float4 c0 = *(const float4*)(row0);
    float4 c1 = *(const float4*)(row1);

    #pragma unroll 1
    for (int j = 0; j < 8; ++j) {
        const int jn = (j + 1) & 7;            // wrap: last prefetch redundant, in-bounds
        float4 n0 = *(const float4*)(row0 + 4 * jn);
        float4 n1 = *(const float4*)(row1 + 4 * jn);

        // person chunk: broadcast from the lane that owns it (no 2nd HBM stream)
        const float p0x = rl(c0.x, sp0), p0y = rl(c0.y, sp0),
                    p0z = rl(c0.z, sp0), p0w = rl(c0.w, sp0);
        const float p1x = rl(c1.x, sp1), p1y = rl(c1.y, sp1),
                    p1z = rl(c1.z, sp1), p1w = rl(c1.w, sp1);

        const float* wrow = &sW1t[4 * j];
        #pragma unroll
        for (int h = 0; h < HID; ++h) {
            float4 wa = *(const float4*)(wrow + h * 64);        // person rows 4j..
            float4 wb = *(const float4*)(wrow + h * 64 + 32);   // wire rows 32+4j..
            acc0[h] += p0x * wa.x + p0y * wa.y + p0z * wa.z + p0w * wa.w
                     + c0.x * wb.x + c0.y * wb.y + c0.z * wb.z + c0.w * wb.w;
            acc1[h] += p1x * wa.x + p1y * wa.y + p1z * wa.z + p1w * wa.w
                     + c1.x * wb.x + c1.y * wb.y + c1.z * wb.z + c1.w * wb.w;
        }
        c0 = n0; c1 = n1;
    }

    // relu -> W2 -> logit per lane(=wire) -> wave softmax -> loss
    {
        float v = sB2;
        #pragma unroll
        for (int h = 0; h < HID; ++h) v += fmaxf(acc0[h], 0.f) * sW2[h];
        float m = v;
        #pragma unroll
        for (int off = 32; off > 0; off >>= 1) m = fmaxf(m, __shfl_xor(m, off));
        float s = __expf(v - m);
        #pragma unroll
        for (int off = 32; off > 0; off >>= 1) s += __shfl_xor(s, off);
        float lv = rl(v, sl0);
        if (lane == 0) out[b0] = m + __logf(s) - lv;
    }
    {
        float v = sB2;
        #pragma unroll
        for (int h = 0; h < HID; ++h) v += fmaxf(acc1[h], 0.f) * sW2[h];
        float m = v;
        #pragma unroll
        for (int off = 32; off > 0; off >>= 1) m = fmaxf(m, __shfl_xor(m, off));
        float s = __expf(v - m);
        #pragma unroll
        for (int off = 32; off > 0; off >>= 1) s += __shfl_xor(s, off);
        float lv = rl(v, sl1);
        if (lane == 0) out[b0 + 1] = m + __logf(s) - lv;
    }
}

extern "C" void kernel_launch(void* const* d_in, const int* in_sizes, int n_in,
                              void* d_out, int out_size, void* d_ws, size_t ws_size,
                              hipStream_t stream) {
    const float* outputs = (const float*)d_in[0];
    const int*   tests   = (const int*)d_in[1];
    const float* W1      = (const float*)d_in[2];
    const float* b1      = (const float*)d_in[3];
    const float* W2      = (const float*)d_in[4];
    const float* b2      = (const float*)d_in[5];
    float* out = (float*)d_out;

    // 8 batches per block (4 waves x NB=2) -> 1024 blocks
    isnet_kernel<<<BATCH / (4 * NB), 256, 0, stream>>>(
        outputs, tests, W1, b1, W2, b2, out);
}

// Round 6
// 103.258 us; speedup vs baseline: 2.1164x; 1.5414x over previous
//
#include <hip/hip_runtime.h>

#define WIRE_DIM  32
#define NUM_WIRES 64
#define BATCH     8192
#define HID       10
#define STRIDE    36   // LDS row stride in floats: 32 + 4 pad -> conflict-free
                       // reads (banks 4*(lane+j)%32, distinct per 8-lane phase)
                       // and writes (banks 4*((i>>3)+(i&7))%32, ditto). 144 B
                       // row stride keeps float4 alignment.

// broadcast-read a float from a wave-uniform lane index -> scalar
__device__ __forceinline__ float rl(float x, int slane) {
    return __uint_as_float(__builtin_amdgcn_readlane(__float_as_uint(x), slane));
}

__global__ __launch_bounds__(256) void isnet_kernel(
    const float* __restrict__ outputs,
    const int*   __restrict__ tests,
    const float* __restrict__ W1,
    const float* __restrict__ b1,
    const float* __restrict__ W2,
    const float* __restrict__ b2,
    float*       __restrict__ out)
{
    // wave-private staging buffers: 4 waves x 64 rows x 36 floats = 36 KB
    __shared__ __align__(16) float stage[4][NUM_WIRES * STRIDE];

    const int tid  = threadIdx.x;
    const int lane = tid & 63;
    const int wave = tid >> 6;
    float* buf = stage[wave];

    // one batch per wave, grid = BATCH/4 = 2048 blocks
    const int b = blockIdx.x * 4 + wave;

    const int sp = __builtin_amdgcn_readfirstlane(tests[2 * b]);      // person
    const int sl = __builtin_amdgcn_readfirstlane(tests[2 * b + 1]);  // location

    // ---- coalesced stage: 8 x contiguous-1KB loads -> padded LDS rows ----
    // (round-5 FETCH was 227 MB vs 67 MB ideal: lane*128B-stride loads
    //  over-fetched ~3.4x at sector granularity. This is the fix.)
    const float* grow = outputs + (size_t)b * (NUM_WIRES * WIRE_DIM);
    {
        const int r = lane >> 3;        // row group within slab
        const int c = lane & 7;         // 16B chunk within row
        #pragma unroll
        for (int t = 0; t < 8; ++t) {
            float4 v = *(const float4*)(grow + t * 256 + lane * 4);
            *(float4*)&buf[(t * 8 + r) * STRIDE + c * 4] = v;
        }
    }
    // buffer is wave-private: no __syncthreads; compiler inserts lgkmcnt wait

    // ---- main loop: weights via wave-uniform (scalar s_load) accesses ----
    float acc[HID];
    #pragma unroll
    for (int h = 0; h < HID; ++h) acc[h] = b1[h];      // uniform -> s_load

    #pragma unroll 1
    for (int j = 0; j < 8; ++j) {
        float4 x = *(const float4*)&buf[lane * STRIDE + j * 4]; // own wire chunk
        float4 p = *(const float4*)&buf[sp   * STRIDE + j * 4]; // person (broadcast)
        const float* wp = W1 + (4 * j) * HID;        // person-half rows 4j..4j+3
        const float* ww = W1 + (32 + 4 * j) * HID;   // wire-half rows 32+4j..
        #pragma unroll
        for (int h = 0; h < HID; ++h) {
            acc[h] += p.x * wp[0 * HID + h] + p.y * wp[1 * HID + h]
                    + p.z * wp[2 * HID + h] + p.w * wp[3 * HID + h]
                    + x.x * ww[0 * HID + h] + x.y * ww[1 * HID + h]
                    + x.z * ww[2 * HID + h] + x.w * ww[3 * HID + h];
        }
    }

    // ---- relu -> W2 -> logit per lane(=wire) -> wave softmax -> loss ----
    float v = b2[0];
    #pragma unroll
    for (int h = 0; h < HID; ++h) v += fmaxf(acc[h], 0.f) * W2[h];

    float m = v;
    #pragma unroll
    for (int off = 32; off > 0; off >>= 1) m = fmaxf(m, __shfl_xor(m, off));
    float s = __expf(v - m);
    #pragma unroll
    for (int off = 32; off > 0; off >>= 1) s += __shfl_xor(s, off);
    float lv = rl(v, sl);                        // logit at `location`
    if (lane == 0) out[b] = m + __logf(s) - lv;  // -log_softmax[loc]
}

extern "C" void kernel_launch(void* const* d_in, const int* in_sizes, int n_in,
                              void* d_out, int out_size, void* d_ws, size_t ws_size,
                              hipStream_t stream) {
    const float* outputs = (const float*)d_in[0];
    const int*   tests   = (const int*)d_in[1];
    const float* W1      = (const float*)d_in[2];
    const float* b1      = (const float*)d_in[3];
    const float* W2      = (const float*)d_in[4];
    const float* b2      = (const float*)d_in[5];
    float* out = (float*)d_out;

    // 4 batches per block (4 waves x 1 batch) -> 2048 blocks
    isnet_kernel<<<BATCH / 4, 256, 0, stream>>>(
        outputs, tests, W1, b1, W2, b2, out);
}

// Round 7
// 102.705 us; speedup vs baseline: 2.1278x; 1.0054x over previous
//
#include <hip/hip_runtime.h>

#define WIRE_DIM  32
#define NUM_WIRES 64
#define BATCH     8192
#define HID       10
#define STRIDE    36   // 32 + 4 pad: conflict-free b128 reads/writes (uniform
                       // 8 dwords/bank per wave access), rows stay 16B-aligned
#define NWAVES    4096 // total waves; each handles batch w and w+NWAVES

// broadcast-read a float from a wave-uniform lane index -> scalar
__device__ __forceinline__ float rl(float x, int slane) {
    return __uint_as_float(__builtin_amdgcn_readlane(__float_as_uint(x), slane));
}

__global__ __launch_bounds__(256) void isnet_kernel(
    const float* __restrict__ outputs,
    const int*   __restrict__ tests,
    const float* __restrict__ W1,
    const float* __restrict__ bias1,
    const float* __restrict__ W2,
    const float* __restrict__ bias2,
    float*       __restrict__ out)
{
    // wave-private staging: 4 waves x 64 rows x 36 floats = 36 KB/block
    __shared__ __align__(16) float stage[4][NUM_WIRES * STRIDE];

    const int tid  = threadIdx.x;
    const int lane = tid & 63;
    const int wave = tid >> 6;
    float* buf = stage[wave];

    const int w0 = blockIdx.x * 4 + wave;       // wave id 0..4095
    const int r  = lane >> 3;                   // LDS row-group within slab
    const int cc = lane & 7;                    // 16B chunk within row

    // compute one batch whose wire data sits in buf (rolled j-loop: rounds
    // 1/2/4 proved full unrolling of the load-rich body => scheduler hoists
    // => 256 VGPR + spill; rolled stays at ~70 live)
    auto run = [&](int bb) {
        const int sp = __builtin_amdgcn_readfirstlane(tests[2 * bb]);
        const int sl = __builtin_amdgcn_readfirstlane(tests[2 * bb + 1]);

        float acc[HID];
        #pragma unroll
        for (int h = 0; h < HID; ++h) acc[h] = bias1[h];   // uniform -> s_load

        #pragma unroll 1
        for (int j = 0; j < 8; ++j) {
            float4 x = *(const float4*)&buf[lane * STRIDE + j * 4]; // own wire
            float4 p = *(const float4*)&buf[sp   * STRIDE + j * 4]; // person (bcast)
            const float* wp = W1 + (4 * j) * HID;       // person rows 4j..4j+3
            const float* ww = W1 + (32 + 4 * j) * HID;  // wire rows 32+4j..
            #pragma unroll
            for (int h = 0; h < HID; ++h) {
                acc[h] += p.x * wp[0 * HID + h] + p.y * wp[1 * HID + h]
                        + p.z * wp[2 * HID + h] + p.w * wp[3 * HID + h]
                        + x.x * ww[0 * HID + h] + x.y * ww[1 * HID + h]
                        + x.z * ww[2 * HID + h] + x.w * ww[3 * HID + h];
            }
        }

        float v = bias2[0];
        #pragma unroll
        for (int h = 0; h < HID; ++h) v += fmaxf(acc[h], 0.f) * W2[h];

        float m = v;
        #pragma unroll
        for (int off = 32; off > 0; off >>= 1) m = fmaxf(m, __shfl_xor(m, off));
        float s = __expf(v - m);
        #pragma unroll
        for (int off = 32; off > 0; off >>= 1) s += __shfl_xor(s, off);
        float lv = rl(v, sl);                            // logit at `location`
        if (lane == 0) out[bb] = m + __logf(s) - lv;     // -log_softmax[loc]
    };

    float4 c[8];

    // ---- stage batch 1 (coalesced: 8 x contiguous-1KB wave loads) ----
    const float* g1 = outputs + (size_t)w0 * (NUM_WIRES * WIRE_DIM) + lane * 4;
    #pragma unroll
    for (int t = 0; t < 8; ++t) c[t] = *(const float4*)(g1 + t * 256);
    #pragma unroll
    for (int t = 0; t < 8; ++t)
        *(float4*)&buf[(t * 8 + r) * STRIDE + cc * 4] = c[t];

    // ---- prefetch batch 2 NOW: its HBM latency hides under batch-1 compute,
    //      and the CU's HBM pipe stays fed during the compute phase ----
    const float* g2 = outputs + (size_t)(w0 + NWAVES) * (NUM_WIRES * WIRE_DIM)
                    + lane * 4;
    #pragma unroll
    for (int t = 0; t < 8; ++t) c[t] = *(const float4*)(g2 + t * 256);

    run(w0);                                   // compute batch 1

    #pragma unroll
    for (int t = 0; t < 8; ++t)                // batch 2 regs -> LDS
        *(float4*)&buf[(t * 8 + r) * STRIDE + cc * 4] = c[t];

    run(w0 + NWAVES);                          // compute batch 2
}

extern "C" void kernel_launch(void* const* d_in, const int* in_sizes, int n_in,
                              void* d_out, int out_size, void* d_ws, size_t ws_size,
                              hipStream_t stream) {
    const float* outputs = (const float*)d_in[0];
    const int*   tests   = (const int*)d_in[1];
    const float* W1      = (const float*)d_in[2];
    const float* b1      = (const float*)d_in[3];
    const float* W2      = (const float*)d_in[4];
    const float* b2      = (const float*)d_in[5];
    float* out = (float*)d_out;

    // 1024 blocks x 4 waves x 2 batches = 8192; 4 blocks/CU (36 KB LDS each)
    // => the WHOLE grid is resident in one generation, loads stream
    isnet_kernel<<<NWAVES / 4, 256, 0, stream>>>(
        outputs, tests, W1, b1, W2, b2, out);
}